// Round 3
// baseline (73.911 us; speedup 1.0000x reference)
//
#include <hip/hip_runtime.h>
#include <math.h>

#define NB_B 8
#define NB_C 256
#define NB_HW 9216          // 96*96
#define TOTPIX 73728        // 8*9216
#define NBLK 1024           // 32*32 blocks per batch
#define NTRI 3072           // block-column triples per plane (9216/3)
// lower median of 9216 flat elems = sorted idx 4607 = block rank 511 (4607/9)

// ---------------- kernel 1: channel-chunk reduction, 12 contiguous px/thread ----
// Each wg handles a 3072-pixel tile (1/3 plane) x CPC channels; each thread owns
// 12 consecutive pixels -> reduces to 4 block-column triple sums in-register.
// part[chunk][b][3072 triples] = sum over CPC channels of per-triple sum of d^2.
template<int CPC>
__global__ __launch_bounds__(256, 4) void k_loss_tri(const float* __restrict__ rec,
                                                     const float* __restrict__ al,
                                                     float* __restrict__ part) {
  const int t = threadIdx.x;
  const int T = blockIdx.x;       // 0..23  (b*3 + seg)
  const int chunk = blockIdx.y;
  const int b = T / 3;
  const int seg = T % 3;
  const size_t base = ((size_t)(b * NB_C + chunk * CPC)) * NB_HW + seg * NTRI + t * 12;
  const float* pr = rec + base;
  const float* pa = al + base;

  float acc0 = 0.f, acc1 = 0.f, acc2 = 0.f, acc3 = 0.f;
#pragma unroll 2
  for (int c = 0; c < CPC; ++c) {
    const float4* r4 = (const float4*)(pr + (size_t)c * NB_HW);
    const float4* a4 = (const float4*)(pa + (size_t)c * NB_HW);
    float4 r0 = r4[0], r1 = r4[1], r2 = r4[2];
    float4 a0 = a4[0], a1 = a4[1], a2 = a4[2];
    float d;
    d = r0.x - a0.x; acc0 = fmaf(d, d, acc0);
    d = r0.y - a0.y; acc0 = fmaf(d, d, acc0);
    d = r0.z - a0.z; acc0 = fmaf(d, d, acc0);
    d = r0.w - a0.w; acc1 = fmaf(d, d, acc1);
    d = r1.x - a1.x; acc1 = fmaf(d, d, acc1);
    d = r1.y - a1.y; acc1 = fmaf(d, d, acc1);
    d = r1.z - a1.z; acc2 = fmaf(d, d, acc2);
    d = r1.w - a1.w; acc2 = fmaf(d, d, acc2);
    d = r2.x - a2.x; acc2 = fmaf(d, d, acc2);
    d = r2.y - a2.y; acc3 = fmaf(d, d, acc3);
    d = r2.z - a2.z; acc3 = fmaf(d, d, acc3);
    d = r2.w - a2.w; acc3 = fmaf(d, d, acc3);
  }
  float4 o = make_float4(acc0, acc1, acc2, acc3);
  // triple index within plane: seg*1024 + 4t .. +3  -> float4 slot t
  ((float4*)(part + (size_t)chunk * (NB_B * NTRI) + (size_t)b * NTRI + seg * 1024))[t] = o;
}

// ---------------- kernel 2: fold chunks + 3 h-rows -> 3x3 block means ----------
__global__ __launch_bounds__(256) void k_blocks(const float* __restrict__ part,
                                                float* __restrict__ blocks, int nch) {
  int id = blockIdx.x * 256 + threadIdx.x;             // 0..8191
  if (id >= NB_B * NBLK) return;
  int b = id >> 10;
  int r = id & 1023;
  int bi = r >> 5, bj = r & 31;
  int tbase = (bi * 3) * 32 + bj;                      // triple index of top row
  float s = 0.f;
  for (int ch = 0; ch < nch; ++ch) {
    const float* lp = part + (size_t)ch * (NB_B * NTRI) + (size_t)b * NTRI + tbase;
    s += lp[0] + lp[32] + lp[64];
  }
  blocks[id] = s * (1.0f / (256.0f * 9.0f));           // mean over C then over 3x3
}

// ---------------- kernel 3: per-batch sort + stats + weighted sum ----------------
__global__ __launch_bounds__(256) void k_stats(const float* __restrict__ blocks,
                                               double* __restrict__ bsums) {
  __shared__ float s[NBLK];
  __shared__ double red[256];
  const int b = blockIdx.x;
  const int t = threadIdx.x;
  for (int i = t; i < NBLK; i += 256) s[i] = blocks[b * NBLK + i];
  __syncthreads();

  // bitonic sort ascending (1024 elems, 256 threads, 4 pairs/thread per step)
  for (int k = 2; k <= NBLK; k <<= 1) {
    for (int j = k >> 1; j > 0; j >>= 1) {
      for (int base = 0; base < NBLK; base += 256) {
        int idx = base + t;
        int ixj = idx ^ j;
        if (ixj > idx) {
          float a = s[idx], c2 = s[ixj];
          bool up = ((idx & k) == 0);
          if ((a > c2) == up) { s[idx] = c2; s[ixj] = a; }
        }
      }
      __syncthreads();
    }
  }

  // mean
  double lp = 0.0;
  for (int i = t; i < NBLK; i += 256) lp += (double)s[i];
  red[t] = lp; __syncthreads();
  for (int w = 128; w > 0; w >>= 1) { if (t < w) red[t] += red[t + w]; __syncthreads(); }
  double mean = red[0] / 1024.0;
  __syncthreads();

  // sum of squared deviations over blocks; flat variance = 9*SS/9215 (ddof=1)
  double ss = 0.0;
  for (int i = t; i < NBLK; i += 256) { double d = (double)s[i] - mean; ss += d * d; }
  red[t] = ss; __syncthreads();
  for (int w = 128; w > 0; w >>= 1) { if (t < w) red[t] += red[t + w]; __syncthreads(); }
  double var = 9.0 * red[0] / 9215.0;
  float stdv = (float)sqrt(var);
  float safe = fmaxf(stdv, 1e-3f);
  float med = s[511];                                  // lower median of the 9x-repeated flat
  __syncthreads();

  // weighted sum: each block contributes 9 * v * (1 + 2*sigmoid((v-med)/safe))
  double wsum = 0.0;
  for (int i = t; i < NBLK; i += 256) {
    float v = s[i];
    float z = (v - med) / safe;
    float sig = 1.0f / (1.0f + expf(-z));
    wsum += (double)(9.0f * v) * (double)(1.0f + 2.0f * sig);
  }
  red[t] = wsum; __syncthreads();
  for (int w = 128; w > 0; w >>= 1) { if (t < w) red[t] += red[t + w]; __syncthreads(); }
  if (t == 0) bsums[b] = red[0];
}

// ---------------- kernel 4: combine batches ----------------
__global__ void k_final(const double* __restrict__ bsums, float* __restrict__ out) {
  if (threadIdx.x == 0 && blockIdx.x == 0) {
    double st = 0.0;
    for (int b = 0; b < NB_B; ++b) st += bsums[b];
    out[0] = (float)(st / (double)TOTPIX);
  }
}

extern "C" void kernel_launch(void* const* d_in, const int* in_sizes, int n_in,
                              void* d_out, int out_size, void* d_ws, size_t ws_size,
                              hipStream_t stream) {
  const float* rec = (const float*)d_in[0];
  const float* al  = (const float*)d_in[1];
  float* out = (float*)d_out;
  char* ws = (char*)d_ws;

  // ws layout: part[nch][8*3072] f32 | blocks[8192] f32 | bsums[8] f64
  auto need = [](int nch) {
    return (size_t)nch * NB_B * NTRI * 4 + (size_t)NB_B * NBLK * 4 + 64;
  };
  int nch = (ws_size >= need(64)) ? 64 : (ws_size >= need(32)) ? 32 : 16;

  float*  part   = (float*)ws;
  float*  blocks = (float*)(ws + (size_t)nch * NB_B * NTRI * 4);
  double* bsums  = (double*)((char*)blocks + (size_t)NB_B * NBLK * 4);

  if (nch == 64)
    k_loss_tri<4><<<dim3(24, 64), 256, 0, stream>>>(rec, al, part);
  else if (nch == 32)
    k_loss_tri<8><<<dim3(24, 32), 256, 0, stream>>>(rec, al, part);
  else
    k_loss_tri<16><<<dim3(24, 16), 256, 0, stream>>>(rec, al, part);

  k_blocks<<<(NB_B * NBLK + 255) / 256, 256, 0, stream>>>(part, blocks, nch);
  k_stats<<<NB_B, 256, 0, stream>>>(blocks, bsums);
  k_final<<<1, 64, 0, stream>>>(bsums, out);
}

// Round 4
// 59.617 us; speedup vs baseline: 1.2398x; 1.2398x over previous
//
#include <hip/hip_runtime.h>
#include <math.h>

#define NB_B 8
#define NB_C 256
#define NB_HW 9216          // 96*96
#define PLANE_F4 2304       // float4s per plane
#define NTRI 3072           // 3-px triples per plane
#define NBLK 1024           // 32*32 blocks per batch
// lower median of 9216 flat elems = sorted idx 4607 = block rank 511 (4607/9)

// ---------------- kernel 1: streaming channel-chunk reduction ----------------
// wg = (b, chunk). Each of 4 waves owns a 9KB quarter-plane and sweeps it with
// 9 consecutive unit-stride float4 loads per tensor per channel. Per-f4 sums
// accumulate in registers (acc[9], static idx); LDS epilogue folds px->triples.
// part[chunk][b][3072] = sum over CPC channels of per-triple sum of d^2.
template<int CPC>
__global__ __launch_bounds__(256, 2) void k_loss_stream(const float* __restrict__ rec,
                                                        const float* __restrict__ al,
                                                        float* __restrict__ part) {
  __shared__ float4 lds[PLANE_F4];                    // 36 KB: per-px loss of this chunk
  const int t = threadIdx.x;
  const int w = t >> 6;                               // wave 0..3
  const int l = t & 63;
  const int b = blockIdx.x;                           // 0..7
  const int chunk = blockIdx.y;                       // 0..nch-1
  const size_t base_f4 = ((size_t)(b * NB_C + chunk * CPC)) * PLANE_F4 + w * 576 + l;
  const float4* r4 = (const float4*)rec + base_f4;
  const float4* a4 = (const float4*)al + base_f4;

  float4 acc[9];
#pragma unroll
  for (int i = 0; i < 9; ++i) acc[i] = make_float4(0.f, 0.f, 0.f, 0.f);

#pragma unroll 2
  for (int c = 0; c < CPC; ++c) {
#pragma unroll
    for (int i = 0; i < 9; ++i) {
      const size_t off = (size_t)c * PLANE_F4 + i * 64;
      float4 r = r4[off];
      float4 a = a4[off];
      float d;
      d = r.x - a.x; acc[i].x = fmaf(d, d, acc[i].x);
      d = r.y - a.y; acc[i].y = fmaf(d, d, acc[i].y);
      d = r.z - a.z; acc[i].z = fmaf(d, d, acc[i].z);
      d = r.w - a.w; acc[i].w = fmaf(d, d, acc[i].w);
    }
  }
#pragma unroll
  for (int i = 0; i < 9; ++i) lds[w * 576 + i * 64 + l] = acc[i];
  __syncthreads();

  // thread t owns px [t*36, t*36+36) = f4 [t*9, t*9+9) -> 12 triple sums
  const float* lf = (const float*)lds + t * 36;
  float tri[12];
#pragma unroll
  for (int j = 0; j < 12; ++j) tri[j] = lf[3 * j] + lf[3 * j + 1] + lf[3 * j + 2];
  float4* outp = (float4*)(part + (size_t)chunk * (NB_B * NTRI) + (size_t)b * NTRI + t * 12);
  outp[0] = make_float4(tri[0], tri[1], tri[2], tri[3]);
  outp[1] = make_float4(tri[4], tri[5], tri[6], tri[7]);
  outp[2] = make_float4(tri[8], tri[9], tri[10], tri[11]);
}

// ---------------- kernel 2: fold nch chunks -> 4 group partials -------------
__global__ __launch_bounds__(256) void k_fold(const float* __restrict__ part,
                                              float* __restrict__ part2, int nch) {
  const int tid = blockIdx.x * 256 + threadIdx.x;     // 0..24575 (triple slot)
  const int g = blockIdx.y;                           // 0..3
  const int per = nch >> 2;
  const float* p = part + (size_t)(g * per) * (NB_B * NTRI) + tid;
  float s = 0.f;
  for (int k = 0; k < per; ++k) s += p[(size_t)k * (NB_B * NTRI)];
  part2[(size_t)g * (NB_B * NTRI) + tid] = s;
}

// ---------------- kernel 3: blocks + sort + stats + weighted sum ------------
__global__ __launch_bounds__(256) void k_stats(const float* __restrict__ part2,
                                               double* __restrict__ bsums) {
  __shared__ float s[NBLK];
  __shared__ double red[256];
  const int b = blockIdx.x;
  const int t = threadIdx.x;

  // build 1024 block means for batch b from the 4 group partials
  for (int blk = t; blk < NBLK; blk += 256) {
    int bi = blk >> 5, bj = blk & 31;
    int tbase = b * NTRI + bi * 96 + bj;              // triple idx of top row
    float sum = 0.f;
#pragma unroll
    for (int g = 0; g < 4; ++g) {
      const float* p = part2 + (size_t)g * (NB_B * NTRI) + tbase;
      sum += p[0] + p[32] + p[64];
    }
    s[blk] = sum * (1.0f / (256.0f * 9.0f));
  }
  __syncthreads();

  // bitonic sort ascending (1024 elems, 256 threads)
  for (int k = 2; k <= NBLK; k <<= 1) {
    for (int j = k >> 1; j > 0; j >>= 1) {
      for (int base = 0; base < NBLK; base += 256) {
        int idx = base + t;
        int ixj = idx ^ j;
        if (ixj > idx) {
          float a = s[idx], c2 = s[ixj];
          bool up = ((idx & k) == 0);
          if ((a > c2) == up) { s[idx] = c2; s[ixj] = a; }
        }
      }
      __syncthreads();
    }
  }

  // mean
  double lp = 0.0;
  for (int i = t; i < NBLK; i += 256) lp += (double)s[i];
  red[t] = lp; __syncthreads();
  for (int w = 128; w > 0; w >>= 1) { if (t < w) red[t] += red[t + w]; __syncthreads(); }
  double mean = red[0] / 1024.0;
  __syncthreads();

  // flat variance = 9*SS/9215 (ddof=1 over the 9x-repeated values)
  double ss = 0.0;
  for (int i = t; i < NBLK; i += 256) { double d = (double)s[i] - mean; ss += d * d; }
  red[t] = ss; __syncthreads();
  for (int w = 128; w > 0; w >>= 1) { if (t < w) red[t] += red[t + w]; __syncthreads(); }
  double var = 9.0 * red[0] / 9215.0;
  float stdv = (float)sqrt(var);
  float safe = fmaxf(stdv, 1e-3f);
  float med = s[511];                                 // lower median
  __syncthreads();

  // each block contributes 9 * v * (1 + 2*sigmoid((v-med)/safe))
  double wsum = 0.0;
  for (int i = t; i < NBLK; i += 256) {
    float v = s[i];
    float z = (v - med) / safe;
    float sig = 1.0f / (1.0f + expf(-z));
    wsum += (double)(9.0f * v) * (double)(1.0f + 2.0f * sig);
  }
  red[t] = wsum; __syncthreads();
  for (int w = 128; w > 0; w >>= 1) { if (t < w) red[t] += red[t + w]; __syncthreads(); }
  if (t == 0) bsums[b] = red[0];
}

// ---------------- kernel 4: combine batches ----------------
__global__ void k_final(const double* __restrict__ bsums, float* __restrict__ out) {
  if (threadIdx.x == 0 && blockIdx.x == 0) {
    double st = 0.0;
    for (int b = 0; b < NB_B; ++b) st += bsums[b];
    out[0] = (float)(st / (double)(NB_B * NB_HW));
  }
}

extern "C" void kernel_launch(void* const* d_in, const int* in_sizes, int n_in,
                              void* d_out, int out_size, void* d_ws, size_t ws_size,
                              hipStream_t stream) {
  const float* rec = (const float*)d_in[0];
  const float* al  = (const float*)d_in[1];
  float* out = (float*)d_out;
  char* ws = (char*)d_ws;

  // ws: part[nch][24576] f32 | part2[4][24576] f32 | bsums[8] f64
  auto need = [](int nch) {
    return (size_t)(nch + 4) * (NB_B * NTRI) * 4 + 64;
  };
  int nch = (ws_size >= need(64)) ? 64 : (ws_size >= need(32)) ? 32
          : (ws_size >= need(16)) ? 16 : 4;

  float*  part  = (float*)ws;
  float*  part2 = (float*)(ws + (size_t)nch * (NB_B * NTRI) * 4);
  double* bsums = (double*)((char*)part2 + (size_t)4 * (NB_B * NTRI) * 4);

  if (nch == 64)
    k_loss_stream<4><<<dim3(NB_B, 64), 256, 0, stream>>>(rec, al, part);
  else if (nch == 32)
    k_loss_stream<8><<<dim3(NB_B, 32), 256, 0, stream>>>(rec, al, part);
  else if (nch == 16)
    k_loss_stream<16><<<dim3(NB_B, 16), 256, 0, stream>>>(rec, al, part);
  else
    k_loss_stream<64><<<dim3(NB_B, 4), 256, 0, stream>>>(rec, al, part);

  k_fold<<<dim3((NB_B * NTRI) / 256, 4), 256, 0, stream>>>(part, part2, nch);
  k_stats<<<NB_B, 256, 0, stream>>>(part2, bsums);
  k_final<<<1, 64, 0, stream>>>(bsums, out);
}

// Round 5
// 57.843 us; speedup vs baseline: 1.2778x; 1.0307x over previous
//
#include <hip/hip_runtime.h>
#include <math.h>

#define NB_B 8
#define NB_C 256
#define NB_HW 9216          // 96*96
#define PLANE_F4 2304       // float4s per plane
#define NBLK 1024           // 32*32 blocks per batch
// lower median of 9216 flat elems = sorted idx 4607 = block rank 511 (4607/9)

// ---------------- kernel 0: zero the block accumulator ----------------
__global__ void k_zero(float* __restrict__ blocks) {
  int id = blockIdx.x * 256 + threadIdx.x;
  if (id < NB_B * NBLK) blocks[id] = 0.f;
}

// ---------------- kernel 1: streaming reduction -> block atomics ------------
// wg = (b, chunk of 4 channels). Each of 4 waves streams a 9KB quarter-plane
// with 9 consecutive unit-stride float4 loads per tensor per channel, acc in
// regs; LDS holds the per-pixel chunk loss; epilogue reduces 3x3 blocks and
// atomicAdds 1024 block partials into blocks[b][1024].
template<int CPC>
__global__ __launch_bounds__(256, 2) void k_loss_blk(const float* __restrict__ rec,
                                                     const float* __restrict__ al,
                                                     float* __restrict__ blocks) {
  __shared__ float4 lds[PLANE_F4];                    // 36 KB: per-px loss of this chunk
  const int t = threadIdx.x;
  const int w = t >> 6;                               // wave 0..3
  const int l = t & 63;
  const int b = blockIdx.x;                           // 0..7
  const int chunk = blockIdx.y;                       // 0..63
  const size_t base_f4 = ((size_t)(b * NB_C + chunk * CPC)) * PLANE_F4 + w * 576 + l;
  const float4* r4 = (const float4*)rec + base_f4;
  const float4* a4 = (const float4*)al + base_f4;

  float4 acc[9];
#pragma unroll
  for (int i = 0; i < 9; ++i) acc[i] = make_float4(0.f, 0.f, 0.f, 0.f);

#pragma unroll 2
  for (int c = 0; c < CPC; ++c) {
#pragma unroll
    for (int i = 0; i < 9; ++i) {
      const size_t off = (size_t)c * PLANE_F4 + i * 64;
      float4 r = r4[off];
      float4 a = a4[off];
      float d;
      d = r.x - a.x; acc[i].x = fmaf(d, d, acc[i].x);
      d = r.y - a.y; acc[i].y = fmaf(d, d, acc[i].y);
      d = r.z - a.z; acc[i].z = fmaf(d, d, acc[i].z);
      d = r.w - a.w; acc[i].w = fmaf(d, d, acc[i].w);
    }
  }
#pragma unroll
  for (int i = 0; i < 9; ++i) lds[w * 576 + i * 64 + l] = acc[i];
  __syncthreads();

  // plane (row-major floats) is at (const float*)lds. Each thread reduces 4
  // 3x3 blocks: blk = t + 256*k. Lanes 0..31 hit distinct banks (stride 3);
  // lanes 32..63 alias 2-way (free).
  const float* pf = (const float*)lds;
  float* dst = blocks + b * NBLK;
#pragma unroll
  for (int k = 0; k < 4; ++k) {
    int blk = t + 256 * k;
    int bi = blk >> 5, bj = blk & 31;
    const float* p = pf + (3 * bi) * 96 + 3 * bj;
    float s = p[0] + p[1] + p[2]
            + p[96] + p[97] + p[98]
            + p[192] + p[193] + p[194];
    atomicAdd(dst + blk, s);
  }
}

// ---------------- kernel 2: per-batch sort + stats + weighted sum -----------
__global__ __launch_bounds__(256) void k_stats(const float* __restrict__ blocks,
                                               double* __restrict__ bsums) {
  __shared__ float s[NBLK];
  __shared__ double red[256];
  const int b = blockIdx.x;
  const int t = threadIdx.x;
  for (int i = t; i < NBLK; i += 256)
    s[i] = blocks[b * NBLK + i] * (1.0f / (256.0f * 9.0f));   // block mean
  __syncthreads();

  // bitonic sort ascending (1024 elems, 256 threads)
  for (int k = 2; k <= NBLK; k <<= 1) {
    for (int j = k >> 1; j > 0; j >>= 1) {
      for (int base = 0; base < NBLK; base += 256) {
        int idx = base + t;
        int ixj = idx ^ j;
        if (ixj > idx) {
          float a = s[idx], c2 = s[ixj];
          bool up = ((idx & k) == 0);
          if ((a > c2) == up) { s[idx] = c2; s[ixj] = a; }
        }
      }
      __syncthreads();
    }
  }

  // mean
  double lp = 0.0;
  for (int i = t; i < NBLK; i += 256) lp += (double)s[i];
  red[t] = lp; __syncthreads();
  for (int w = 128; w > 0; w >>= 1) { if (t < w) red[t] += red[t + w]; __syncthreads(); }
  double mean = red[0] / 1024.0;
  __syncthreads();

  // flat variance = 9*SS/9215 (ddof=1 over the 9x-repeated values)
  double ss = 0.0;
  for (int i = t; i < NBLK; i += 256) { double d = (double)s[i] - mean; ss += d * d; }
  red[t] = ss; __syncthreads();
  for (int w = 128; w > 0; w >>= 1) { if (t < w) red[t] += red[t + w]; __syncthreads(); }
  double var = 9.0 * red[0] / 9215.0;
  float stdv = (float)sqrt(var);
  float safe = fmaxf(stdv, 1e-3f);
  float med = s[511];                                 // lower median
  __syncthreads();

  // each block contributes 9 * v * (1 + 2*sigmoid((v-med)/safe))
  double wsum = 0.0;
  for (int i = t; i < NBLK; i += 256) {
    float v = s[i];
    float z = (v - med) / safe;
    float sig = 1.0f / (1.0f + expf(-z));
    wsum += (double)(9.0f * v) * (double)(1.0f + 2.0f * sig);
  }
  red[t] = wsum; __syncthreads();
  for (int w = 128; w > 0; w >>= 1) { if (t < w) red[t] += red[t + w]; __syncthreads(); }
  if (t == 0) bsums[b] = red[0];
}

// ---------------- kernel 3: combine batches ----------------
__global__ void k_final(const double* __restrict__ bsums, float* __restrict__ out) {
  if (threadIdx.x == 0 && blockIdx.x == 0) {
    double st = 0.0;
    for (int b = 0; b < NB_B; ++b) st += bsums[b];
    out[0] = (float)(st / (double)(NB_B * NB_HW));
  }
}

extern "C" void kernel_launch(void* const* d_in, const int* in_sizes, int n_in,
                              void* d_out, int out_size, void* d_ws, size_t ws_size,
                              hipStream_t stream) {
  const float* rec = (const float*)d_in[0];
  const float* al  = (const float*)d_in[1];
  float* out = (float*)d_out;
  char* ws = (char*)d_ws;

  // ws: blocks[8][1024] f32 | bsums[8] f64   (33 KB)
  float*  blocks = (float*)ws;
  double* bsums  = (double*)(ws + (size_t)NB_B * NBLK * 4);

  k_zero<<<(NB_B * NBLK + 255) / 256, 256, 0, stream>>>(blocks);
  k_loss_blk<4><<<dim3(NB_B, 64), 256, 0, stream>>>(rec, al, blocks);
  k_stats<<<NB_B, 256, 0, stream>>>(blocks, bsums);
  k_final<<<1, 64, 0, stream>>>(bsums, out);
}